// Round 1
// baseline (522.199 us; speedup 1.0000x reference)
//
#include <hip/hip_runtime.h>
#include <hip/hip_bf16.h>
#include <cstdint>
#include <cstddef>

#define B_ 4
#define T_ 2048
#define E_ 1024
#define H_ 8
#define D_ 128

typedef unsigned short u16;
typedef __bf16 bf16x8 __attribute__((ext_vector_type(8)));
typedef float f32x4 __attribute__((ext_vector_type(4)));

__device__ __forceinline__ u16 f2bf(float f) {
  union { float f; uint32_t u; } a; a.f = f;
  uint32_t u = a.u;
  uint32_t r = (u + 0x7fffu + ((u >> 16) & 1u)) >> 16;  // RNE
  return (u16)r;
}

// ---- fp32 -> bf16 conversion (n must be multiple of 4) ----
__global__ void cvt_kernel(const float* __restrict__ src, u16* __restrict__ dst, int n) {
  int i = (blockIdx.x * blockDim.x + threadIdx.x) * 4;
  if (i >= n) return;
  float4 v = *(const float4*)(src + i);
  uint2 o;
  o.x = (uint32_t)f2bf(v.x) | ((uint32_t)f2bf(v.y) << 16);
  o.y = (uint32_t)f2bf(v.z) | ((uint32_t)f2bf(v.w) << 16);
  *(uint2*)(dst + i) = o;
}

// ---- sinusoidal PE table: pe[t][2i]=sin(t*f_i), pe[t][2i+1]=cos(t*f_i) ----
__global__ void pe_kernel(float* __restrict__ pe) {
  int idx = blockIdx.x * blockDim.x + threadIdx.x;
  if (idx >= T_ * 64) return;
  int t = idx >> 6, i = idx & 63;
  float f = expf(-logf(10000.0f) * (float)i / 64.0f);
  float ang = (float)t * f;
  pe[t * 128 + 2 * i]     = sinf(ang);
  pe[t * 128 + 2 * i + 1] = cosf(ang);
}

// ---- NT GEMM: C[m][n] = sum_k A[m][k]*Bm[n][k], A/Bm bf16 row-major K-contig.
// 128x128 tile, BK=32, 4 waves (2x2), each wave 64x64 = 4x4 16x16x32 MFMA frags.
// MODE 0: N=1280, epilogue routes to Q(+PE)/K(+1 odd)/V bf16 buffers.
// MODE 1: N=1024, fp32 write to Cout.
template<int MODE>
__global__ __launch_bounds__(256) void gemm_nt(
    const u16* __restrict__ A, const u16* __restrict__ Bm,
    u16* __restrict__ Qb, u16* __restrict__ Kb, u16* __restrict__ Vb,
    const float* __restrict__ pe, float* __restrict__ Cout, int K)
{
  __shared__ u16 Al[128 * 40];  // pad 32->40 elems: stride 80B, 16B-aligned, conflict-light
  __shared__ u16 Bl[128 * 40];
  const int t = threadIdx.x;
  const int l = t & 63, w = t >> 6;
  const int wr = w >> 1, wc = w & 1;
  const int bm = blockIdx.x * 128, bn = blockIdx.y * 128;
  const int lr = l & 15, lg = l >> 4;

  f32x4 acc[4][4] = {};

  for (int k0 = 0; k0 < K; k0 += 32) {
    #pragma unroll
    for (int it = 0; it < 2; ++it) {
      int c = it * 256 + t;          // 512 chunks of 8 bf16 = 128x32 tile
      int row = c >> 2;
      int col = (c & 3) * 8;
      *(uint4*)(&Al[row * 40 + col]) = *(const uint4*)(A + (size_t)(bm + row) * K + k0 + col);
      *(uint4*)(&Bl[row * 40 + col]) = *(const uint4*)(Bm + (size_t)(bn + row) * K + k0 + col);
    }
    __syncthreads();
    bf16x8 af[4], bfr[4];
    #pragma unroll
    for (int m = 0; m < 4; ++m)
      af[m] = *(const bf16x8*)(&Al[(wr * 64 + m * 16 + lr) * 40 + lg * 8]);
    #pragma unroll
    for (int n = 0; n < 4; ++n)
      bfr[n] = *(const bf16x8*)(&Bl[(wc * 64 + n * 16 + lr) * 40 + lg * 8]);
    #pragma unroll
    for (int m = 0; m < 4; ++m) {
      #pragma unroll
      for (int n = 0; n < 4; ++n)
        acc[m][n] = __builtin_amdgcn_mfma_f32_16x16x32_bf16(af[m], bfr[n], acc[m][n], 0, 0, 0);
    }
    __syncthreads();
  }

  // D layout (m89-verified): col = lane&15, row = (lane>>4)*4 + reg
  #pragma unroll
  for (int m = 0; m < 4; ++m) {
    #pragma unroll
    for (int n = 0; n < 4; ++n) {
      #pragma unroll
      for (int r = 0; r < 4; ++r) {
        int gm = bm + wr * 64 + m * 16 + lg * 4 + r;
        int gn = bn + wc * 64 + n * 16 + lr;
        float v = acc[m][n][r];
        if constexpr (MODE == 0) {
          int b = gm >> 11, tq = gm & (T_ - 1);
          if (gn < 1024) {            // Q: [b][h][t][d], add PE
            int h = gn >> 7, d = gn & 127;
            Qb[(((size_t)(b * H_ + h) * T_ + tq) << 7) + d] = f2bf(v + pe[(tq << 7) + d]);
          } else if (gn < 1152) {     // K: [b*T+t][d], +1 on odd d (pe(1,D))
            int d = gn - 1024;
            Kb[((size_t)gm << 7) + d] = f2bf(v + (float)(d & 1));
          } else {                    // V: [b*T+t][d]
            int d = gn - 1152;
            Vb[((size_t)gm << 7) + d] = f2bf(v);
          }
        } else {
          Cout[(size_t)gm * 1024 + gn] = v;
        }
      }
    }
  }
}

// ---- Flash attention, causal, MQA (1 KV head).
// Block = (qt, h, b): 64 q-rows; 4 waves x 16 rows. KV tiles of 32.
__global__ __launch_bounds__(256) void attn_kernel(
    const u16* __restrict__ Qb, const u16* __restrict__ Kb,
    const u16* __restrict__ Vb, u16* __restrict__ Ob)
{
  __shared__ u16 Kl[32 * 136];   // [kv][d], pad 128->136 (272B stride, 16B-aligned)
  __shared__ u16 Vt[128 * 40];   // [d][kv], pad 32->40
  __shared__ u16 Pl[4 * 640];    // per-wave P [16][40]
  const int t = threadIdx.x;
  const int l = t & 63, w = t >> 6;
  const int lr = l & 15, lg = l >> 4;
  const int qt = blockIdx.x, h = blockIdx.y, b = blockIdx.z;

  // Q fragments in regs: A-frag row = lr, k-chunk per lg
  const u16* qbase = Qb + (((size_t)(b * H_ + h) * T_ + qt * 64 + w * 16 + lr) << 7);
  bf16x8 qf[4];
  #pragma unroll
  for (int db = 0; db < 4; ++db)
    qf[db] = *(const bf16x8*)(qbase + db * 32 + lg * 8);

  float mrow[4] = {-1e30f, -1e30f, -1e30f, -1e30f};
  float lrow[4] = {0.f, 0.f, 0.f, 0.f};
  f32x4 o[8] = {};

  const int tqw = qt * 64 + w * 16 + 15;   // max q-row this wave
  const int ntiles = (qt * 64 + 64) / 32;
  const float scale = 0.08838834764831845f; // 1/sqrt(128)
  u16* pw = &Pl[w * 640];

  for (int kt = 0; kt < ntiles; ++kt) {
    const int kvbase = b * T_ + kt * 32;
    #pragma unroll
    for (int it = 0; it < 2; ++it) {
      int c = it * 256 + t;                 // 512 chunks of 8 = 32x128 tile
      int row = c >> 4;
      int col = (c & 15) * 8;
      *(uint4*)(&Kl[row * 136 + col]) = *(const uint4*)(Kb + ((size_t)(kvbase + row) << 7) + col);
      uint4 vv4 = *(const uint4*)(Vb + ((size_t)(kvbase + row) << 7) + col);
      const u16* vv = (const u16*)&vv4;
      #pragma unroll
      for (int j = 0; j < 8; ++j)
        Vt[(col + j) * 40 + row] = vv[j];   // transpose into [d][kv]
    }
    __syncthreads();

    if (kt * 32 <= tqw) {
      // S = Q K^T : S layout col(lane&15)=kv, row=(lg*4+r)=q
      f32x4 s0 = {}, s1 = {};
      #pragma unroll
      for (int db = 0; db < 4; ++db) {
        bf16x8 kf0 = *(const bf16x8*)(&Kl[lr * 136 + db * 32 + lg * 8]);
        bf16x8 kf1 = *(const bf16x8*)(&Kl[(16 + lr) * 136 + db * 32 + lg * 8]);
        s0 = __builtin_amdgcn_mfma_f32_16x16x32_bf16(qf[db], kf0, s0, 0, 0, 0);
        s1 = __builtin_amdgcn_mfma_f32_16x16x32_bf16(qf[db], kf1, s1, 0, 0, 0);
      }
      const int tq0 = qt * 64 + w * 16 + lg * 4;
      const int tk0 = kt * 32 + lr;
      float p0[4], p1[4], corr[4], pm[4];
      #pragma unroll
      for (int r = 0; r < 4; ++r) {
        float v0 = (tk0 <= tq0 + r)      ? s0[r] * scale : -1e30f;
        float v1 = (tk0 + 16 <= tq0 + r) ? s1[r] * scale : -1e30f;
        p0[r] = v0; p1[r] = v1;
        pm[r] = fmaxf(v0, v1);
      }
      #pragma unroll
      for (int d = 1; d < 16; d <<= 1) {
        #pragma unroll
        for (int r = 0; r < 4; ++r) pm[r] = fmaxf(pm[r], __shfl_xor(pm[r], d));
      }
      float rs[4];
      #pragma unroll
      for (int r = 0; r < 4; ++r) {
        float mn = fmaxf(mrow[r], pm[r]);
        corr[r] = __expf(mrow[r] - mn);
        mrow[r] = mn;
        p0[r] = __expf(p0[r] - mn);  // masked -> exp(-huge) = 0
        p1[r] = __expf(p1[r] - mn);
        rs[r] = p0[r] + p1[r];
      }
      #pragma unroll
      for (int d = 1; d < 16; d <<= 1) {
        #pragma unroll
        for (int r = 0; r < 4; ++r) rs[r] += __shfl_xor(rs[r], d);
      }
      #pragma unroll
      for (int r = 0; r < 4; ++r) lrow[r] = lrow[r] * corr[r] + rs[r];
      #pragma unroll
      for (int db = 0; db < 8; ++db) {
        #pragma unroll
        for (int r = 0; r < 4; ++r) o[db][r] *= corr[r];
      }
      // P -> LDS (S-layout) -> re-read as A-frag (same wave, no barrier needed)
      #pragma unroll
      for (int r = 0; r < 4; ++r) {
        pw[(lg * 4 + r) * 40 + lr]      = f2bf(p0[r]);
        pw[(lg * 4 + r) * 40 + 16 + lr] = f2bf(p1[r]);
      }
      bf16x8 pf = *(const bf16x8*)(&pw[lr * 40 + lg * 8]);
      #pragma unroll
      for (int db = 0; db < 8; ++db) {
        bf16x8 vf = *(const bf16x8*)(&Vt[(db * 16 + lr) * 40 + lg * 8]);
        o[db] = __builtin_amdgcn_mfma_f32_16x16x32_bf16(pf, vf, o[db], 0, 0, 0);
      }
    }
    __syncthreads();
  }

  // epilogue: O /= lsum, write [b][t][h*128+d] bf16
  const int tqb = qt * 64 + w * 16 + lg * 4;
  #pragma unroll
  for (int db = 0; db < 8; ++db) {
    #pragma unroll
    for (int r = 0; r < 4; ++r) {
      float val = o[db][r] / lrow[r];
      Ob[(((size_t)(b * T_ + tqb + r)) << 10) + h * 128 + db * 16 + lr] = f2bf(val);
    }
  }
}

extern "C" void kernel_launch(void* const* d_in, const int* in_sizes, int n_in,
                              void* d_out, int out_size, void* d_ws, size_t ws_size,
                              hipStream_t stream) {
  const float* x  = (const float*)d_in[0];
  const float* Wq = (const float*)d_in[1];
  const float* Wk = (const float*)d_in[2];
  const float* Wv = (const float*)d_in[3];
  const float* Wo = (const float*)d_in[4];

  char* ws = (char*)d_ws;
  size_t off = 0;
  auto alloc = [&](size_t bytes) {
    char* p = ws + off;
    off += (bytes + 255) & ~(size_t)255;
    return p;
  };
  u16*   xbf  = (u16*)  alloc(8388608ull * 2);   // x bf16 [8192][1024]
  u16*   Wcat = (u16*)  alloc(1310720ull * 2);   // [Wq;Wk;Wv] bf16 [1280][1024]
  u16*   Wobf = (u16*)  alloc(1048576ull * 2);   // Wo bf16 [1024][1024]
  float* pe   = (float*)alloc(262144ull * 4);    // PE table [2048][128] fp32
  u16*   Qbuf = (u16*)  alloc(8388608ull * 2);   // Q bf16 [B][H][T][D]
  u16*   Kbuf = (u16*)  alloc(1048576ull * 2);   // K bf16 [B*T][D]
  u16*   Vbuf = (u16*)  alloc(1048576ull * 2);   // V bf16 [B*T][D]
  u16*   Abuf = (u16*)  alloc(8388608ull * 2);   // attn out bf16 [B*T][H*D]

  cvt_kernel<<<8192, 256, 0, stream>>>(x, xbf, 8388608);
  cvt_kernel<<<1024, 256, 0, stream>>>(Wq, Wcat, 1048576);
  cvt_kernel<<<128,  256, 0, stream>>>(Wk, Wcat + 1048576, 131072);
  cvt_kernel<<<128,  256, 0, stream>>>(Wv, Wcat + 1179648, 131072);
  cvt_kernel<<<1024, 256, 0, stream>>>(Wo, Wobf, 1048576);
  pe_kernel<<<512, 256, 0, stream>>>(pe);

  gemm_nt<0><<<dim3(64, 10), 256, 0, stream>>>(xbf, Wcat, Qbuf, Kbuf, Vbuf, pe, nullptr, 1024);
  attn_kernel<<<dim3(32, 8, 4), 256, 0, stream>>>(Qbuf, Kbuf, Vbuf, Abuf);
  gemm_nt<1><<<dim3(64, 8), 256, 0, stream>>>(Abuf, Wobf, nullptr, nullptr, nullptr, nullptr,
                                              (float*)d_out, 1024);
}

// Round 3
// 171.908 us; speedup vs baseline: 3.0377x; 3.0377x over previous
//
#include <hip/hip_runtime.h>
#include <hip/hip_bf16.h>
#include <cstdint>
#include <cstddef>

#define B_ 4
#define T_ 2048
#define E_ 1024
#define H_ 8
#define D_ 128

typedef unsigned short u16;
typedef __bf16 bf16x8 __attribute__((ext_vector_type(8)));
typedef float f32x4 __attribute__((ext_vector_type(4)));

#define MFMA16(a, b, c) __builtin_amdgcn_mfma_f32_16x16x32_bf16((a), (b), (c), 0, 0, 0)

__device__ __forceinline__ u16 f2bf(float f) {
  union { float f; uint32_t u; } a; a.f = f;
  uint32_t u = a.u;
  uint32_t r = (u + 0x7fffu + ((u >> 16) & 1u)) >> 16;  // RNE
  return (u16)r;
}

// pack 2 f32 -> 2 bf16 in one u32 (lo = src0, hi = src1)
__device__ __forceinline__ uint32_t pkbf(float lo, float hi) {
  uint32_t r;
  asm volatile("v_cvt_pk_bf16_f32 %0, %1, %2" : "=v"(r) : "v"(lo), "v"(hi));
  return r;
}

// ---- fp32 -> bf16 conversion (n multiple of 4) ----
__global__ void cvt_kernel(const float* __restrict__ src, u16* __restrict__ dst, int n) {
  int i = (blockIdx.x * blockDim.x + threadIdx.x) * 4;
  if (i >= n) return;
  float4 v = *(const float4*)(src + i);
  uint2 o;
  o.x = (uint32_t)f2bf(v.x) | ((uint32_t)f2bf(v.y) << 16);
  o.y = (uint32_t)f2bf(v.z) | ((uint32_t)f2bf(v.w) << 16);
  *(uint2*)(dst + i) = o;
}

// ---- sinusoidal PE table ----
__global__ void pe_kernel(float* __restrict__ pe) {
  int idx = blockIdx.x * blockDim.x + threadIdx.x;
  if (idx >= T_ * 64) return;
  int t = idx >> 6, i = idx & 63;
  float f = expf(-logf(10000.0f) * (float)i / 64.0f);
  float ang = (float)t * f;
  pe[t * 128 + 2 * i]     = sinf(ang);
  pe[t * 128 + 2 * i + 1] = cosf(ang);
}

// ---- NT GEMM, 128x128 tile, BK=32, 4 waves (2x2), 64x64/wave.
// MODE 0: N=1280 -> Q(+PE) [b][h][t][d], K(+1 odd) [bt][d], V^T [b][d][t].
// MODE 1: N=1024 -> fp32 Cout.
template<int MODE>
__global__ __launch_bounds__(256) void gemm_nt(
    const u16* __restrict__ A, const u16* __restrict__ Bm,
    u16* __restrict__ Qb, u16* __restrict__ Kb, u16* __restrict__ VTb,
    const float* __restrict__ pe, float* __restrict__ Cout, int K)
{
  __shared__ u16 Al[128 * 40];
  __shared__ u16 Bl[128 * 40];
  const int t = threadIdx.x;
  const int l = t & 63, w = t >> 6;
  const int wr = w >> 1, wc = w & 1;
  const int bm = blockIdx.x * 128, bn = blockIdx.y * 128;
  const int lr = l & 15, lg = l >> 4;

  f32x4 acc[4][4] = {};

  for (int k0 = 0; k0 < K; k0 += 32) {
    #pragma unroll
    for (int it = 0; it < 2; ++it) {
      int c = it * 256 + t;
      int row = c >> 2;
      int col = (c & 3) * 8;
      *(uint4*)(&Al[row * 40 + col]) = *(const uint4*)(A + (size_t)(bm + row) * K + k0 + col);
      *(uint4*)(&Bl[row * 40 + col]) = *(const uint4*)(Bm + (size_t)(bn + row) * K + k0 + col);
    }
    __syncthreads();
    bf16x8 af[4], bfr[4];
    #pragma unroll
    for (int m = 0; m < 4; ++m)
      af[m] = *(const bf16x8*)(&Al[(wr * 64 + m * 16 + lr) * 40 + lg * 8]);
    #pragma unroll
    for (int n = 0; n < 4; ++n)
      bfr[n] = *(const bf16x8*)(&Bl[(wc * 64 + n * 16 + lr) * 40 + lg * 8]);
    #pragma unroll
    for (int m = 0; m < 4; ++m) {
      #pragma unroll
      for (int n = 0; n < 4; ++n)
        acc[m][n] = MFMA16(af[m], bfr[n], acc[m][n]);
    }
    __syncthreads();
  }

  // D layout: col = lane&15, row = (lane>>4)*4 + reg
  #pragma unroll
  for (int m = 0; m < 4; ++m) {
    #pragma unroll
    for (int n = 0; n < 4; ++n) {
      const int gm0 = bm + wr * 64 + m * 16 + lg * 4;   // 4-aligned, tile never crosses b
      const int gn = bn + wc * 64 + n * 16 + lr;
      if constexpr (MODE == 0) {
        const int b = gm0 >> 11, tq0 = gm0 & (T_ - 1);
        if (gn < 1024) {            // Q
          int hh = gn >> 7, d = gn & 127;
          #pragma unroll
          for (int r = 0; r < 4; ++r)
            Qb[(((size_t)(b * H_ + hh) * T_ + tq0 + r) << 7) + d] =
                f2bf(acc[m][n][r] + pe[((tq0 + r) << 7) + d]);
        } else if (gn < 1152) {     // K (+pe(1,D): +1 on odd d)
          int d = gn - 1024;
          #pragma unroll
          for (int r = 0; r < 4; ++r)
            Kb[((size_t)(gm0 + r) << 7) + d] = f2bf(acc[m][n][r] + (float)(d & 1));
        } else {                    // V^T [b][d][t], packed 8B store
          int d = gn - 1152;
          uint2 pk;
          pk.x = pkbf(acc[m][n][0], acc[m][n][1]);
          pk.y = pkbf(acc[m][n][2], acc[m][n][3]);
          *(uint2*)(VTb + ((size_t)(b * 128 + d) << 11) + tq0) = pk;
        }
      } else {
        #pragma unroll
        for (int r = 0; r < 4; ++r)
          Cout[(size_t)(gm0 + r) * 1024 + gn] = acc[m][n][r];
      }
    }
  }
}

// ---- Flash attention, causal, MQA. Block = (pair p, b): 8 waves = 8 heads,
// each wave owns two 16-row q-frags (tiles p and 127-p; balanced). KV tile 64.
// Swapped QK^T (S^T = mfma(K,Q)): lane owns one q-row -> in-lane softmax.
__global__ __launch_bounds__(512, 2) void attn_kernel(
    const u16* __restrict__ Qb, const u16* __restrict__ Kb,
    const u16* __restrict__ VTg, u16* __restrict__ Ob)
{
  __shared__ u16 Kl[64 * 136];    // [kv][d], 272B row = 17 16B-units -> uniform banks
  __shared__ u16 VTl[128 * 72];   // [d][kv], 144B row = 9 units
  __shared__ u16 Pl[8 * 16 * 72]; // per-wave P[q][kv], reused for both frags
  const int t = threadIdx.x;
  const int l = t & 63, w = t >> 6;       // wave = head
  const int lr = l & 15, lg = l >> 4;
  const int p = blockIdx.x, b = blockIdx.y;
  const int h = w;
  const int q0A = p * 16, q0B = (127 - p) * 16;
  const int ntA = (q0A + 16 + 63) >> 6, ntB = (q0B + 16 + 63) >> 6;
  const float scale = 0.08838834764831845f;  // 1/sqrt(128)

  // Q frags (B-operand: lane lr = q col, k = d)
  const u16* qbA = Qb + (((size_t)(b * H_ + h) * T_ + q0A + lr) << 7);
  const u16* qbB = Qb + (((size_t)(b * H_ + h) * T_ + q0B + lr) << 7);
  bf16x8 qfA[4], qfB[4];
  #pragma unroll
  for (int kc = 0; kc < 4; ++kc) {
    qfA[kc] = *(const bf16x8*)(qbA + kc * 32 + lg * 8);
    qfB[kc] = *(const bf16x8*)(qbB + kc * 32 + lg * 8);
  }

  float mA = -3e38f, mB = -3e38f, lA = 0.f, lB = 0.f;
  f32x4 oA[8] = {}, oB[8] = {};
  u16* pw = &Pl[w * 16 * 72];

  // softmax + P-write + PV for one 16-row frag against the staged 64-kv tile
  auto process = [&](f32x4 (&s)[4], float& m, float& lsum, f32x4 (&o)[8],
                     int q0F, int kt) {
    const int qv = q0F + lr;
    float pv[16];
    float pm = -3e38f;
    #pragma unroll
    for (int kvf = 0; kvf < 4; ++kvf) {
      #pragma unroll
      for (int r = 0; r < 4; ++r) {
        int kv = kt * 64 + kvf * 16 + lg * 4 + r;
        float sv = (kv <= qv) ? s[kvf][r] * scale : -3e38f;
        pv[kvf * 4 + r] = sv;
        pm = fmaxf(pm, sv);
      }
    }
    pm = fmaxf(pm, __shfl_xor(pm, 16));
    pm = fmaxf(pm, __shfl_xor(pm, 32));
    float mn = fmaxf(m, pm);
    float corr = __expf(m - mn);
    float ps = 0.f;
    #pragma unroll
    for (int i = 0; i < 16; ++i) {
      pv[i] = __expf(pv[i] - mn);   // masked -> exp(-huge) = 0
      ps += pv[i];
    }
    ps += __shfl_xor(ps, 16);
    ps += __shfl_xor(ps, 32);
    lsum = lsum * corr + ps;
    m = mn;
    #pragma unroll
    for (int df = 0; df < 8; ++df) {
      #pragma unroll
      for (int r = 0; r < 4; ++r) o[df][r] *= corr;
    }
    // P[q=lr][kv]: 4 consecutive kv per lane -> one b64 write per kvf
    #pragma unroll
    for (int kvf = 0; kvf < 4; ++kvf) {
      uint2 pk;
      pk.x = pkbf(pv[kvf * 4 + 0], pv[kvf * 4 + 1]);
      pk.y = pkbf(pv[kvf * 4 + 2], pv[kvf * 4 + 3]);
      *(uint2*)(&pw[lr * 72 + kvf * 16 + lg * 4]) = pk;
    }
    // O^T += mfma(V^T frag, P frag)
    #pragma unroll
    for (int kc = 0; kc < 2; ++kc) {
      bf16x8 pf = *(const bf16x8*)(&pw[lr * 72 + kc * 32 + lg * 8]);
      #pragma unroll
      for (int df = 0; df < 8; ++df) {
        bf16x8 vf = *(const bf16x8*)(&VTl[(df * 16 + lr) * 72 + kc * 32 + lg * 8]);
        o[df] = MFMA16(vf, pf, o[df]);
      }
    }
  };

  for (int kt = 0; kt < ntB; ++kt) {
    // stage K[64][128] and VT[128][64] (all 8 waves cooperate)
    #pragma unroll
    for (int it = 0; it < 2; ++it) {
      int cc = it * 512 + t;
      {
        int row = cc >> 4, u = cc & 15;
        *(uint4*)(&Kl[row * 136 + u * 8]) =
            *(const uint4*)(Kb + ((size_t)(b * T_ + kt * 64 + row) << 7) + u * 8);
      }
      {
        int d = cc >> 3, u = cc & 7;
        *(uint4*)(&VTl[d * 72 + u * 8]) =
            *(const uint4*)(VTg + ((size_t)(b * 128 + d) << 11) + kt * 64 + u * 8);
      }
    }
    __syncthreads();

    const bool actA = kt < ntA;   // block-uniform
    f32x4 sA[4] = {}, sB[4] = {};
    #pragma unroll
    for (int kvf = 0; kvf < 4; ++kvf) {
      bf16x8 kf[4];
      #pragma unroll
      for (int kc = 0; kc < 4; ++kc)
        kf[kc] = *(const bf16x8*)(&Kl[(kvf * 16 + lr) * 136 + kc * 32 + lg * 8]);
      #pragma unroll
      for (int kc = 0; kc < 4; ++kc)
        sB[kvf] = MFMA16(kf[kc], qfB[kc], sB[kvf]);
      if (actA) {
        #pragma unroll
        for (int kc = 0; kc < 4; ++kc)
          sA[kvf] = MFMA16(kf[kc], qfA[kc], sA[kvf]);
      }
    }
    process(sB, mB, lB, oB, q0B, kt);
    if (actA) process(sA, mA, lA, oA, q0A, kt);
    __syncthreads();
  }

  // epilogue: O^T/l -> Ob[b*T+q][h*128+d], 4 consecutive d per lane -> 8B store
  float rA = 1.0f / lA, rB = 1.0f / lB;
  #pragma unroll
  for (int df = 0; df < 8; ++df) {
    uint2 pk;
    pk.x = pkbf(oB[df][0] * rB, oB[df][1] * rB);
    pk.y = pkbf(oB[df][2] * rB, oB[df][3] * rB);
    *(uint2*)(Ob + ((size_t)(b * T_ + q0B + lr) << 10) + h * 128 + df * 16 + lg * 4) = pk;
    pk.x = pkbf(oA[df][0] * rA, oA[df][1] * rA);
    pk.y = pkbf(oA[df][2] * rA, oA[df][3] * rA);
    *(uint2*)(Ob + ((size_t)(b * T_ + q0A + lr) << 10) + h * 128 + df * 16 + lg * 4) = pk;
  }
}

extern "C" void kernel_launch(void* const* d_in, const int* in_sizes, int n_in,
                              void* d_out, int out_size, void* d_ws, size_t ws_size,
                              hipStream_t stream) {
  const float* x  = (const float*)d_in[0];
  const float* Wq = (const float*)d_in[1];
  const float* Wk = (const float*)d_in[2];
  const float* Wv = (const float*)d_in[3];
  const float* Wo = (const float*)d_in[4];

  char* ws = (char*)d_ws;
  size_t off = 0;
  auto alloc = [&](size_t bytes) {
    char* p = ws + off;
    off += (bytes + 255) & ~(size_t)255;
    return p;
  };
  u16*   xbf  = (u16*)  alloc(8388608ull * 2);   // x bf16 [8192][1024]
  u16*   Wcat = (u16*)  alloc(1310720ull * 2);   // [Wq;Wk;Wv] bf16 [1280][1024]
  u16*   Wobf = (u16*)  alloc(1048576ull * 2);   // Wo bf16 [1024][1024]
  float* pe   = (float*)alloc(262144ull * 4);    // PE table [2048][128] fp32
  u16*   Qbuf = (u16*)  alloc(8388608ull * 2);   // Q bf16 [B][H][T][D]
  u16*   Kbuf = (u16*)  alloc(1048576ull * 2);   // K bf16 [B*T][D]
  u16*   VTbuf= (u16*)  alloc(1048576ull * 2);   // V^T bf16 [B][D][T]
  u16*   Abuf = (u16*)  alloc(8388608ull * 2);   // attn out bf16 [B*T][H*D]

  cvt_kernel<<<8192, 256, 0, stream>>>(x, xbf, 8388608);
  cvt_kernel<<<1024, 256, 0, stream>>>(Wq, Wcat, 1048576);
  cvt_kernel<<<128,  256, 0, stream>>>(Wk, Wcat + 1048576, 131072);
  cvt_kernel<<<128,  256, 0, stream>>>(Wv, Wcat + 1179648, 131072);
  cvt_kernel<<<1024, 256, 0, stream>>>(Wo, Wobf, 1048576);
  pe_kernel<<<512, 256, 0, stream>>>(pe);

  gemm_nt<0><<<dim3(64, 10), 256, 0, stream>>>(xbf, Wcat, Qbuf, Kbuf, VTbuf, pe, nullptr, 1024);
  attn_kernel<<<dim3(64, 4), 512, 0, stream>>>(Qbuf, Kbuf, VTbuf, Abuf);
  gemm_nt<1><<<dim3(64, 8), 256, 0, stream>>>(Abuf, Wobf, nullptr, nullptr, nullptr, nullptr,
                                              (float*)d_out, 1024);
}